// Round 1
// baseline (193.044 us; speedup 1.0000x reference)
//
#include <hip/hip_runtime.h>

// PointpairAttentionLayer fused kernel (fp32, no MFMA — CDNA4 has no fp32 MFMA)
// B=8, F=G=128, N=1024, K=32, NUM_CLASSES=8, n_perms=36
// Block = 256 threads = 4 waves, handles (b, n0..n0+1).
//   lane = (n_local<<5) | k ; wave w owns g in [32w, 32w+32)
// Softmax over K is a 32-lane shfl_xor reduction (lanes with same n_local).

#define NK 32768            // N*K
#define NEG_SLOPE 0.2f

__global__ __launch_bounds__(256) void fused_gat(
    const float* __restrict__ x,
    const int*   __restrict__ core_types,
    const int*   __restrict__ target_types,
    const float* __restrict__ W,
    const float* __restrict__ a_pair,
    float* __restrict__ out,
    float* __restrict__ att_out)
{
    __shared__ float xs[128][64];   // 32 KB: x[b][f][n0..n0+1][k]

    const int t    = threadIdx.x;
    const int wv   = __builtin_amdgcn_readfirstlane(t >> 6);  // wave id 0..3 (uniform -> s_loads for W)
    const int lane = t & 63;
    const int k    = lane & 31;
    const int nl   = lane >> 5;                 // 0/1
    const int b    = blockIdx.x >> 9;           // 512 blocks per batch
    const int n0   = (blockIdx.x & 511) * 2;
    const int n    = n0 + nl;

    // ---- stage x tile: each wave loads 64 contiguous floats per f-row (256B coalesced)
    {
        const float* xb = x + (size_t)b * 128 * NK + (size_t)n0 * 32;
        const int m  = t & 63;
        const int fb = t >> 6;
        #pragma unroll 4
        for (int r = 0; r < 32; ++r) {
            const int f = fb + (r << 2);
            xs[f][m] = xb[(size_t)f * NK + m];
        }
    }
    __syncthreads();

    // ---- GEMM: acc[j] = Wh[b,n,k, 32*wv+j] = sum_f x[b,f,n,k] * W[f, 32*wv+j]
    float acc[32];
    #pragma unroll
    for (int j = 0; j < 32; ++j) acc[j] = 0.f;

    const float* Wp = W + wv * 32;              // uniform base -> scalar loads
    #pragma unroll 2
    for (int f = 0; f < 128; ++f) {
        const float xv = xs[f][lane];           // conflict-free (2-way alias is free)
        const float* wr = Wp + (f << 7);
        #pragma unroll
        for (int j = 0; j < 32; ++j)
            acc[j] = fmaf(xv, wr[j], acc[j]);
    }

    // ---- pair index (closed form of the triangular table)
    const int c  = core_types[b * 1024 + n];
    const int tt = target_types[(b * 1024 + n) * 32 + k];
    const int lo = min(c, tt);
    const int hi = max(c, tt);
    const int idx = lo * (17 - lo) / 2 + (hi - lo);
    const float* arow = a_pair + idx * 128 + wv * 32;   // L1-resident gather (18 KB table)

    // ---- e = leaky_relu(Wh * a); softmax over k (32-lane groups)
    float att[32];
    #pragma unroll
    for (int j = 0; j < 32; ++j) {
        float e = acc[j] * arow[j];
        att[j] = e > 0.f ? e : NEG_SLOPE * e;
    }
    #pragma unroll
    for (int j = 0; j < 32; ++j) {
        float e = att[j];
        float mx = e;
        #pragma unroll
        for (int s = 16; s >= 1; s >>= 1) mx = fmaxf(mx, __shfl_xor(mx, s));
        const float p = __expf(e - mx);
        float sm = p;
        #pragma unroll
        for (int s = 16; s >= 1; s >>= 1) sm += __shfl_xor(sm, s);
        att[j] = __fdividef(p, sm);
    }

    // ---- out[b, g, n, k] = elu(att * Wh)  (per-j: 256B contiguous per wave)
    float* outp = out + (size_t)b * 128 * NK + (size_t)n * 32 + k;
    #pragma unroll
    for (int j = 0; j < 32; ++j) {
        const float h = att[j] * acc[j];
        outp[(size_t)(wv * 32 + j) * NK] = h > 0.f ? h : __expf(h) - 1.f;
    }

    // ---- attention[b, n, k, g] (lane-contiguous float4; L2 write-combines)
    float* attp = att_out + (((size_t)(b * 1024 + n)) * 32 + k) * 128 + wv * 32;
    #pragma unroll
    for (int j = 0; j < 32; j += 4) {
        float4 v = make_float4(att[j], att[j + 1], att[j + 2], att[j + 3]);
        *(float4*)(attp + j) = v;
    }
}

extern "C" void kernel_launch(void* const* d_in, const int* in_sizes, int n_in,
                              void* d_out, int out_size, void* d_ws, size_t ws_size,
                              hipStream_t stream) {
    const float* x    = (const float*)d_in[0];
    const int*   core = (const int*)  d_in[1];
    const int*   tgt  = (const int*)  d_in[2];
    const float* W    = (const float*)d_in[3];
    const float* ap   = (const float*)d_in[4];
    // d_in[5] (lin_w), d_in[6] (lin_b) feed only attention_viz, which is not returned.

    float* out_p = (float*)d_out;                       // (8,128,1024,32)
    float* att_p = out_p + (size_t)8 * 128 * 1024 * 32; // (8,1024,32,128)

    fused_gat<<<dim3(4096), dim3(256), 0, stream>>>(x, core, tgt, W, ap, out_p, att_p);
}

// Round 2
// 109.036 us; speedup vs baseline: 1.7705x; 1.7705x over previous
//
#include <hip/hip_runtime.h>

// Fused GAT layer, bf16-MFMA GEMM path.
// B=8, F=G=128, N=1024, K=32. Block = 256 thr = 4 waves, owns (b, n0,n0+1) = 64 nk-rows.
// Wave w computes all 64 m-rows x g in [32w,32w+32) via mfma_f32_16x16x32_bf16:
//   acc[mt][gt] : m = 16*mt + (lane>>4)*4 + reg, g = 32w + 16*gt + (lane&15)  [m89 C/D layout]
// A-frag (x^T) from LDS transposed bf16 tile [64][136] (pad 8 -> 2-way-free ds_read_b128).
// B-frag (W) per-lane gather from global (L2-hot), lives in 32 VGPRs across K-loop.
// Softmax over k: 8 regs + shfl_xor(16,32) over the 4-lane group. All fp32 after MFMA.

#define NK 32768
#define NEG_SLOPE 0.2f

using f32x4 = __attribute__((ext_vector_type(4))) float;
using s16x8 = __attribute__((ext_vector_type(8))) short;

__device__ __forceinline__ unsigned short f2bf(float f) {   // RNE float->bf16
    unsigned u = __float_as_uint(f);
    return (unsigned short)((u + 0x7FFFu + ((u >> 16) & 1u)) >> 16);
}

__global__ __launch_bounds__(256) void fused_gat_mfma(
    const float* __restrict__ x,
    const int*   __restrict__ core_types,
    const int*   __restrict__ target_types,
    const float* __restrict__ W,
    const float* __restrict__ a_pair,
    float* __restrict__ out,
    float* __restrict__ att_out)
{
    __shared__ __align__(16) unsigned short xs[64 * 136];   // x^T tile bf16: row m, 128 f + 8 pad

    const int t    = threadIdx.x;
    const int wv   = __builtin_amdgcn_readfirstlane(t >> 6);
    const int lane = t & 63;
    const int l15  = lane & 15;
    const int l4   = lane >> 4;
    const int b    = blockIdx.x >> 9;
    const int n0   = (blockIdx.x & 511) * 2;

    // ---- stage x^T tile as bf16 (transpose via packed b32 LDS writes)
    {
        const float* xb = x + (size_t)b * 128 * NK + (size_t)n0 * 32;
        const int m   = t & 63;
        const int fp0 = t >> 6;
        unsigned int* xs32 = (unsigned int*)xs;
        #pragma unroll
        for (int r = 0; r < 16; ++r) {
            const int fp = fp0 + r * 4;                     // f-pair 0..63
            const float lo = xb[(size_t)(2 * fp)     * NK + m];
            const float hi = xb[(size_t)(2 * fp + 1) * NK + m];
            xs32[m * 68 + fp] = (unsigned int)f2bf(lo) | ((unsigned int)f2bf(hi) << 16);
        }
    }

    // ---- B fragments from W (fp32 [f][g]): lane holds g = 32wv+16gt+l15, k=f = 32fs+8*l4+i
    s16x8 bfrag[2][4];
    #pragma unroll
    for (int gt = 0; gt < 2; ++gt) {
        const int g = wv * 32 + gt * 16 + l15;
        #pragma unroll
        for (int fs = 0; fs < 4; ++fs) {
            #pragma unroll
            for (int i = 0; i < 8; ++i) {
                const int f = fs * 32 + l4 * 8 + i;
                bfrag[gt][fs][i] = (short)f2bf(W[f * 128 + g]);
            }
        }
    }

    __syncthreads();

    // ---- MFMA K-loop
    f32x4 acc[4][2];
    #pragma unroll
    for (int mt = 0; mt < 4; ++mt)
        #pragma unroll
        for (int gt = 0; gt < 2; ++gt)
            acc[mt][gt] = (f32x4){0.f, 0.f, 0.f, 0.f};

    #pragma unroll
    for (int fs = 0; fs < 4; ++fs) {
        s16x8 afrag[4];
        #pragma unroll
        for (int mt = 0; mt < 4; ++mt)
            afrag[mt] = *(const s16x8*)&xs[(16 * mt + l15) * 136 + fs * 32 + l4 * 8];
        #pragma unroll
        for (int mt = 0; mt < 4; ++mt)
            #pragma unroll
            for (int gt = 0; gt < 2; ++gt)
                acc[mt][gt] = __builtin_amdgcn_mfma_f32_16x16x32_bf16(
                    afrag[mt], bfrag[gt][fs], acc[mt][gt], 0, 0, 0);
    }

    // ---- epilogue: e = leaky(Wh*a); softmax over k; out = elu(att*Wh)
    const int c0 = core_types[b * 1024 + n0];
    const int c1 = core_types[b * 1024 + n0 + 1];

    float e[4][2][4];
    #pragma unroll
    for (int mt = 0; mt < 4; ++mt) {
        const int n  = n0 + (mt >> 1);
        const int cc = (mt >> 1) ? c1 : c0;
        const int kb = 16 * (mt & 1) + l4 * 4;
        const int4 tt4 = *(const int4*)&target_types[((size_t)(b * 1024 + n)) * 32 + kb];
        const int ttv[4] = {tt4.x, tt4.y, tt4.z, tt4.w};
        #pragma unroll
        for (int r = 0; r < 4; ++r) {
            const int tt = ttv[r];
            const int lo = min(cc, tt), hi = max(cc, tt);
            const int idx = lo * (17 - lo) / 2 + (hi - lo);
            const float* arow = a_pair + idx * 128 + wv * 32 + l15;
            #pragma unroll
            for (int gt = 0; gt < 2; ++gt) {
                const float ev = acc[mt][gt][r] * arow[gt * 16];
                e[mt][gt][r] = ev > 0.f ? ev : NEG_SLOPE * ev;
            }
        }
    }

    float att[4][2][4];
    #pragma unroll
    for (int nl = 0; nl < 2; ++nl)
        #pragma unroll
        for (int gt = 0; gt < 2; ++gt) {
            float mx = -1e30f;
            #pragma unroll
            for (int h = 0; h < 2; ++h)
                #pragma unroll
                for (int r = 0; r < 4; ++r) mx = fmaxf(mx, e[2 * nl + h][gt][r]);
            mx = fmaxf(mx, __shfl_xor(mx, 16));
            mx = fmaxf(mx, __shfl_xor(mx, 32));
            float sm = 0.f;
            #pragma unroll
            for (int h = 0; h < 2; ++h)
                #pragma unroll
                for (int r = 0; r < 4; ++r) {
                    const float p = __expf(e[2 * nl + h][gt][r] - mx);
                    att[2 * nl + h][gt][r] = p;
                    sm += p;
                }
            sm += __shfl_xor(sm, 16);
            sm += __shfl_xor(sm, 32);
            const float inv = __fdividef(1.f, sm);
            #pragma unroll
            for (int h = 0; h < 2; ++h)
                #pragma unroll
                for (int r = 0; r < 4; ++r) att[2 * nl + h][gt][r] *= inv;
        }

    // ---- stores
    #pragma unroll
    for (int mt = 0; mt < 4; ++mt) {
        const int n  = n0 + (mt >> 1);
        const int kb = 16 * (mt & 1) + l4 * 4;
        #pragma unroll
        for (int gt = 0; gt < 2; ++gt) {
            const int g = wv * 32 + gt * 16 + l15;
            f32x4 ov;
            #pragma unroll
            for (int r = 0; r < 4; ++r) {
                const float h = att[mt][gt][r] * acc[mt][gt][r];
                ov[r] = h > 0.f ? h : __expf(h) - 1.f;
            }
            *(f32x4*)&out[(size_t)b * 128 * NK + (size_t)g * NK + n * 32 + kb] = ov;
        }
        #pragma unroll
        for (int r = 0; r < 4; ++r) {
            const size_t abase = (((size_t)(b * 1024 + n)) * 32 + kb + r) * 128 + wv * 32 + l15;
            att_out[abase]      = att[mt][0][r];
            att_out[abase + 16] = att[mt][1][r];
        }
    }
}

extern "C" void kernel_launch(void* const* d_in, const int* in_sizes, int n_in,
                              void* d_out, int out_size, void* d_ws, size_t ws_size,
                              hipStream_t stream) {
    const float* x    = (const float*)d_in[0];
    const int*   core = (const int*)  d_in[1];
    const int*   tgt  = (const int*)  d_in[2];
    const float* W    = (const float*)d_in[3];
    const float* ap   = (const float*)d_in[4];
    // d_in[5]/d_in[6] (lin_w, lin_b) only feed attention_viz, which is not returned.

    float* out_p = (float*)d_out;                       // (8,128,1024,32)
    float* att_p = out_p + (size_t)8 * 128 * 1024 * 32; // (8,1024,32,128)

    fused_gat_mfma<<<dim3(4096), dim3(256), 0, stream>>>(x, core, tgt, W, ap, out_p, att_p);
}